// Round 1
// baseline (27.080 us; speedup 1.0000x reference)
//
#include <hip/hip_runtime.h>

// Problem constants (from reference): N=32, C=256, P=256, H=W=7, K=7, PAD=3.
// Factorization: w[n,p,c,kh,kw] = x[n,c,kh,kw]*Wk[p] + bk[p]
// => y[n,p,oh,ow] = Wk[p]*S1[n,oh,ow] + bk[p]*S2[n,oh,ow] + b_adap[p]
//    S1[n,oh,ow] = sum_{c,i,j valid} x[n,c,i+oh-3,j+ow-3] * x[n,c,i,j]
//    S2[n,oh,ow] = sum_{c,(i,j) in window} x[n,c,i,j]
// This collapses a 19.7 GFLOP dynamic conv into ~0.07 GFLOP.

#define NCH 256
#define HW  49   // 7*7

__global__ __launch_bounds__(256) void adap_fc_kernel(
    const float* __restrict__ x,   // (N, C, 7, 7)
    const float* __restrict__ Wk,  // (P,)
    const float* __restrict__ bk,  // (P,)
    const float* __restrict__ ba,  // (P,)
    float* __restrict__ y)         // (N, P, 7, 7)
{
    const int n = blockIdx.x;
    const int t = threadIdx.x;          // 256 threads; thread t owns channel t
    const int wave = t >> 6;            // 4 waves/block
    const int lane = t & 63;

    __shared__ float lx[NCH][HW];       // 50176 B: x[n] staged
    __shared__ float p1[4][HW];         // per-wave partials of S1
    __shared__ float p2[4][HW];         // per-wave partials of S2
    __shared__ float s1[HW];
    __shared__ float s2[HW];

    // --- stage x[n] into LDS, coalesced ---
    const float* xn = x + (size_t)n * (NCH * HW);
    for (int idx = t; idx < NCH * HW; idx += 256) {
        lx[idx / HW][idx % HW] = xn[idx];
    }
    __syncthreads();

    // --- pull own channel into registers (compile-time indices only) ---
    float v[HW];
    #pragma unroll
    for (int k = 0; k < HW; ++k) v[k] = lx[t][k];

    // --- per-position autocorrelation + window sum, reduce across block ---
    #pragma unroll
    for (int oh = 0; oh < 7; ++oh) {
        #pragma unroll
        for (int ow = 0; ow < 7; ++ow) {
            const int doh = oh - 3, dow = ow - 3;
            float a1 = 0.f, a2 = 0.f;
            #pragma unroll
            for (int i = 0; i < 7; ++i) {
                const int ii = i + doh;
                if (ii < 0 || ii > 6) continue;      // compile-time pruned
                #pragma unroll
                for (int j = 0; j < 7; ++j) {
                    const int jj = j + dow;
                    if (jj < 0 || jj > 6) continue;  // compile-time pruned
                    const float xs = v[ii * 7 + jj]; // x_pad[oh+i, ow+j]
                    a1 += xs * v[i * 7 + j];
                    a2 += xs;
                }
            }
            // 64-lane butterfly reduce (deterministic)
            #pragma unroll
            for (int off = 32; off > 0; off >>= 1) {
                a1 += __shfl_xor(a1, off);
                a2 += __shfl_xor(a2, off);
            }
            if (lane == 0) {
                p1[wave][oh * 7 + ow] = a1;
                p2[wave][oh * 7 + ow] = a2;
            }
        }
    }
    __syncthreads();

    if (t < HW) {
        s1[t] = p1[0][t] + p1[1][t] + p1[2][t] + p1[3][t];
        s2[t] = p2[0][t] + p2[1][t] + p2[2][t] + p2[3][t];
    }
    __syncthreads();

    // --- fused epilogue: y[n,p,pos] = Wk[p]*S1 + bk[p]*S2 + ba[p], coalesced ---
    float* yn = y + (size_t)n * (NCH * HW);
    for (int idx = t; idx < NCH * HW; idx += 256) {
        const int p   = idx / HW;
        const int pos = idx % HW;
        yn[idx] = Wk[p] * s1[pos] + bk[p] * s2[pos] + ba[p];
    }
}

extern "C" void kernel_launch(void* const* d_in, const int* in_sizes, int n_in,
                              void* d_out, int out_size, void* d_ws, size_t ws_size,
                              hipStream_t stream) {
    const float* x  = (const float*)d_in[0];  // (32,256,7,7)
    const float* Wk = (const float*)d_in[1];  // (256,)
    const float* bk = (const float*)d_in[2];  // (256,)
    const float* ba = (const float*)d_in[3];  // (256,)
    float* y = (float*)d_out;                 // (32,256,7,7)

    adap_fc_kernel<<<32, 256, 0, stream>>>(x, Wk, bk, ba, y);
}

// Round 2
// 26.184 us; speedup vs baseline: 1.0342x; 1.0342x over previous
//
#include <hip/hip_runtime.h>

// N=32, C=256, P=256, H=W=7, K=7, PAD=3.
// Factorization: w[n,p,c,kh,kw] = x[n,c,kh,kw]*Wk[p] + bk[p]
// => y[n,p,oh,ow] = Wk[p]*S1[n,oh,ow] + bk[p]*S2[n,oh,ow] + b_adap[p]
//    S1[n,oh,ow] = sum_{c,i,j valid} x[n,c,i+oh-3,j+ow-3]*x[n,c,i,j]   (autocorr, S1(d)=S1(-d))
//    S2[n,oh,ow] = clipped-window sum of z, z = channel-sum of x[n]
//
// Grid: 256 blocks = 8 per sample. Each block redundantly computes S1/S2
// (cheap, wall-parallel) and writes a 32-plane slice of y. bid = pg*32 + n
// keeps all 8 blocks of a sample on one XCD (bid%8 == n%8) for L2 reuse of x[n].

#define NCH  256
#define HW   49
#define NLAG 25   // unique autocorrelation lags (symmetry)

__global__ __launch_bounds__(256) void adap_fc_kernel(
    const float* __restrict__ x,   // (32,256,7,7)
    const float* __restrict__ Wk,  // (256,)
    const float* __restrict__ bk,  // (256,)
    const float* __restrict__ ba,  // (256,)
    float* __restrict__ y)         // (32,256,7,7)
{
    const int bid  = blockIdx.x;
    const int n    = bid & 31;   // sample
    const int pg   = bid >> 5;   // plane-group: 32 output planes
    const int t    = threadIdx.x;
    const int wave = t >> 6;
    const int lane = t & 63;

    __shared__ float lx[NCH * HW];     // 50176 B, x[n] flat
    __shared__ float p1[4][NLAG];      // per-wave S1 partials
    __shared__ float pz[4][HW];        // per-wave z partials
    __shared__ float s1f[HW];          // S1 expanded to all 49 positions
    __shared__ float zz[HW];           // channel-summed image
    __shared__ float s2[HW];           // window sums
    __shared__ float lwk[32], lbk[32], lba[32];

    // --- stage x[n] (float4, coalesced; 3136 float4 = 12.25 * 256) ---
    const float4* xn4 = (const float4*)(x + (size_t)n * (NCH * HW));
    float4* lx4 = (float4*)lx;
    #pragma unroll
    for (int i = 0; i < 12; ++i) lx4[t + i * 256] = xn4[t + i * 256];
    if (t < 64) lx4[t + 12 * 256] = xn4[t + 12 * 256];
    if (t < 32) {
        const int p = pg * 32 + t;
        lwk[t] = Wk[p]; lbk[t] = bk[p]; lba[t] = ba[p];
    }
    __syncthreads();

    // --- own channel into registers (stride 49 across lanes: conflict-free) ---
    float v[HW];
    #pragma unroll
    for (int k = 0; k < HW; ++k) v[k] = lx[t * HW + k];

    // --- S1: 25 canonical lags, fully unrolled; butterfly reduce over 64 lanes ---
    #pragma unroll
    for (int l = 0; l < NLAG; ++l) {
        const int dh = (l < 4) ? 0 : (l - 4) / 7 + 1;
        const int dw = (l < 4) ? l : (l - 4) % 7 - 3;
        float a = 0.f;
        #pragma unroll
        for (int i = 0; i < 7; ++i) {
            if (i + dh < 0 || i + dh > 6) continue;   // compile-time pruned
            #pragma unroll
            for (int j = 0; j < 7; ++j) {
                if (j + dw < 0 || j + dw > 6) continue;
                a += v[(i + dh) * 7 + (j + dw)] * v[i * 7 + j];
            }
        }
        #pragma unroll
        for (int off = 32; off; off >>= 1) a += __shfl_xor(a, off);
        if (lane == 0) p1[wave][l] = a;
    }

    // --- z partials: butterfly each of 49 positions ---
    #pragma unroll
    for (int pos = 0; pos < HW; ++pos) {
        float a = v[pos];
        #pragma unroll
        for (int off = 32; off; off >>= 1) a += __shfl_xor(a, off);
        if (lane == 0) pz[wave][pos] = a;
    }
    __syncthreads();

    // --- cross-wave sums; expand S1 by symmetry ---
    if (t < HW) {
        int dh = t / 7 - 3, dw = t % 7 - 3;
        if (dh < 0 || (dh == 0 && dw < 0)) { dh = -dh; dw = -dw; }
        const int l = (dh == 0) ? dw : 4 + (dh - 1) * 7 + (dw + 3);
        s1f[t] = p1[0][l] + p1[1][l] + p1[2][l] + p1[3][l];
        zz[t]  = pz[0][t] + pz[1][t] + pz[2][t] + pz[3][t];
    }
    __syncthreads();

    // --- S2: clipped-rectangle sums of zz (49 threads, tiny) ---
    if (t < HW) {
        const int doh = t / 7 - 3, dow = t % 7 - 3;
        const int i0 = max(0, doh), i1 = min(6, 6 + doh);
        const int j0 = max(0, dow), j1 = min(6, 6 + dow);
        float s = 0.f;
        for (int i = i0; i <= i1; ++i)
            for (int j = j0; j <= j1; ++j) s += zz[i * 7 + j];
        s2[t] = s;
    }
    __syncthreads();

    // --- epilogue: this block's 32 planes (1568 floats), coalesced ---
    float* yn = y + ((size_t)n * NCH + pg * 32) * HW;
    #pragma unroll
    for (int it = 0; it < 7; ++it) {
        const int idx = t + it * 256;
        if (idx < 32 * HW) {
            const int p = idx / HW, pos = idx - p * HW;
            yn[idx] = lwk[p] * s1f[pos] + lbk[p] * s2[pos] + lba[p];
        }
    }
}

extern "C" void kernel_launch(void* const* d_in, const int* in_sizes, int n_in,
                              void* d_out, int out_size, void* d_ws, size_t ws_size,
                              hipStream_t stream) {
    const float* x  = (const float*)d_in[0];
    const float* Wk = (const float*)d_in[1];
    const float* bk = (const float*)d_in[2];
    const float* ba = (const float*)d_in[3];
    float* y = (float*)d_out;

    adap_fc_kernel<<<256, 256, 0, stream>>>(x, Wk, bk, ba, y);
}